// Round 14
// baseline (229.929 us; speedup 1.0000x reference)
//
#include <hip/hip_runtime.h>
#include <stdint.h>

typedef _Float16 f16;
typedef _Float16 half2_t __attribute__((ext_vector_type(2)));
typedef _Float16 half4 __attribute__((ext_vector_type(4)));
typedef _Float16 half8 __attribute__((ext_vector_type(8)));
typedef float f32x4 __attribute__((ext_vector_type(4)));

#define BATCH 16
#define NQ 64
#define SL 4096
#define DH 128

// Tiled f16 layout for Kt/Vt, per b (halves):
//   off(d, n) = (n>>5)*4096 + (d>>4)*512 + ((n>>3)&3)*128 + (d&15)*8 + (n&7)
// A fragment read (16x16x32 MFMA) is then a coalesced global read base+l*16.

#if __has_builtin(__builtin_amdgcn_fdot2)
#define DOT8(accv, a, b)                                                     \
  {                                                                          \
    accv = __builtin_amdgcn_fdot2(__builtin_shufflevector(a, a, 0, 1),       \
                                  __builtin_shufflevector(b, b, 0, 1), accv, \
                                  false);                                    \
    accv = __builtin_amdgcn_fdot2(__builtin_shufflevector(a, a, 2, 3),       \
                                  __builtin_shufflevector(b, b, 2, 3), accv, \
                                  false);                                    \
    accv = __builtin_amdgcn_fdot2(__builtin_shufflevector(a, a, 4, 5),       \
                                  __builtin_shufflevector(b, b, 4, 5), accv, \
                                  false);                                    \
    accv = __builtin_amdgcn_fdot2(__builtin_shufflevector(a, a, 6, 7),       \
                                  __builtin_shufflevector(b, b, 6, 7), accv, \
                                  false);                                    \
  }
#else
#define DOT8(accv, a, b)                                                     \
  {                                                                          \
    _Pragma("unroll") for (int _k = 0; _k < 8; ++_k) accv +=                 \
        (float)a[_k] * (float)b[_k];                                         \
  }
#endif

// ---------------------------------------------------------------------------
// Kernel P: convert f32 [b][n][d] -> f16 tiled [b][(d,n) tiled]
// ---------------------------------------------------------------------------
__global__ __launch_bounds__(256) void kprep(const float* __restrict__ Kg,
                                             const float* __restrict__ Vg,
                                             f16* __restrict__ Kt,
                                             f16* __restrict__ Vt) {
  __shared__ f16 Ld[128][130];
  const int blk = blockIdx.x;
  const int b = blk >> 6;
  const int tensor = (blk >> 5) & 1;
  const int chunk = blk & 31;
  const float* src = tensor ? Vg : Kg;
  f16* dst = tensor ? Vt : Kt;
  const int t = threadIdx.x;
  const int n0 = chunk * 128;
  {
    const int d = t & 127;
    const int nl = t >> 7;  // 0..1
    const float* s = src + ((size_t)b * SL + n0 + nl) * DH + d;
    for (int it = 0; it < 64; ++it)
      Ld[d][nl + it * 2] = (f16)s[(size_t)it * 2 * DH];
  }
  __syncthreads();
  {
    const int r = t & 15;
    const int kc = (t >> 4) & 3;
    const int w = t >> 6;
    char* dstb = (char*)(dst + (size_t)b * DH * SL);
#pragma unroll
    for (int tl = 0; tl < 4; ++tl)
#pragma unroll
      for (int hh = 0; hh < 2; ++hh) {
        const int dhi = w + hh * 4;
        const int d = dhi * 16 + r;
        const int nl = tl * 32 + kc * 8;
        const half8 v = *(const half8*)&Ld[d][nl];
        *(half8*)(dstb + (size_t)(chunk * 4 + tl) * 8192 + dhi * 1024 +
                  kc * 256 + r * 16) = v;
      }
  }
}

// ---------------------------------------------------------------------------
// Kernel S: E[b][q][n] = (f16)exp(scale * Q.K[n]).  Reads tiled Kt.
// Also writes denomp[ns][b][q] = sum_{n in quarter} E  (deterministic).
// ---------------------------------------------------------------------------
__global__ __launch_bounds__(256) void kscore(const float* __restrict__ Q,
                                              const f16* __restrict__ Kt,
                                              f16* __restrict__ E,
                                              float* __restrict__ denomp) {
  const int blk = (blockIdx.x & 7) * 64 + (blockIdx.x >> 3);
  __shared__ float Qs[8][128];
  __shared__ float wsum[4][4];
  const int b = blk >> 5;
  const int qg = (blk >> 2) & 7;
  const int ns = blk & 3;
  const int t = threadIdx.x;
  for (int i = t; i < 8 * 128; i += 256)
    Qs[i >> 7][i & 127] = Q[((size_t)b * NQ + qg * 8 + (i >> 7)) * DH + (i & 127)];
  __syncthreads();
  const int w = t >> 6, l = t & 63;
  const int q0 = (w >> 1) * 4;
  const int nbase = ns * 1024 + (w & 1) * 512 + l * 8;
  const f16* kb = Kt + (size_t)b * DH * SL + (size_t)(nbase >> 5) * 4096 +
                  (size_t)((nbase >> 3) & 3) * 128;
  float acc[4][8] = {};
  for (int d = 0; d < DH; ++d) {
    const half8 kv = *(const half8*)(kb + (d >> 4) * 512 + (d & 15) * 8);
    float kf[8];
#pragma unroll
    for (int j = 0; j < 8; ++j) kf[j] = (float)kv[j];
#pragma unroll
    for (int qi = 0; qi < 4; ++qi) {
      const float qv = Qs[q0 + qi][d];
#pragma unroll
      for (int j = 0; j < 8; ++j) acc[qi][j] += qv * kf[j];
    }
  }
  const float scl = 0.08838834764831845f;  // 1/sqrt(128)
#pragma unroll
  for (int qi = 0; qi < 4; ++qi) {
    half8 ev;
    float ds = 0.f;
#pragma unroll
    for (int j = 0; j < 8; ++j) {
      ev[j] = (f16)__expf(acc[qi][j] * scl);
      ds += (float)ev[j];
    }
    *(half8*)&E[((size_t)b * NQ + qg * 8 + q0 + qi) * SL + nbase] = ev;
    for (int off = 1; off < 64; off <<= 1) ds += __shfl_xor(ds, off);
    if (l == 0) wsum[w][qi] = ds;
  }
  __syncthreads();
  if (t < 8) {
    const int hw = (t >> 2) * 2;
    denomp[(size_t)ns * BATCH * NQ + (size_t)b * NQ + qg * 8 + t] =
        wsum[hw][t & 3] + wsum[hw + 1][t & 3];
  }
}

// ---------------------------------------------------------------------------
// Kernel G: per (b, 4 q):  T[v][k] = sum_n V[n,v] * (E_n*K[n,k])  via MFMA.
// 512 thr / 8 waves / 1 block per CU; wave 64x32 x 4q.  EV/EK accumulated
// IN-KERNEL via v_dot2 on the same fragments (kev kernel deleted): per tile
// 96 dot2 ops on the VALU pipe co-issued with 32 MFMAs.  kc-group reduce via
// shfl_xor(16/32); EV redistributed to C/D rows via __shfl in the epilogue.
// NO LDS/barriers; ping-pong distance 1; setprio.
// ---------------------------------------------------------------------------
__global__ __launch_bounds__(512, 2) void kjac(
    const f16* __restrict__ Vt, const f16* __restrict__ Kt,
    const f16* __restrict__ E, const float* __restrict__ denomp,
    float* __restrict__ out) {
  const int blk = (blockIdx.x & 7) * 32 + (blockIdx.x >> 3);  // XCD swizzle
  const int b = blk >> 4;
  const int q0 = (blk & 15) * 4;
  const int t = threadIdx.x, w = t >> 6, l = t & 63;
  const int sA = (w >> 2) * 4;  // A row-subtile base (row half: 64 rows)
  const int sB = (w & 3) * 2;   // B col-subtile base (col quarter: 32 cols)
  const char* vtb = (const char*)(Vt + (size_t)b * DH * SL) + sA * 1024 + l * 16;
  const char* ktb = (const char*)(Kt + (size_t)b * DH * SL) + sB * 1024 + l * 16;
  const f16* Eb = E + ((size_t)b * NQ + q0) * SL + (l >> 4) * 8;

  f32x4 acc[4][4][2] = {};
  float evr[4][4] = {};  // EV partial: [q][i] for row (sA+i)*16 + (l&15)
  float ekr[4][2] = {};  // EK partial: [q][j] for col (sB+j)*16 + (l&15)
  half8 vfA[4], kfA[2], efA[4], vfB[4], kfB[2], efB[4];

#define LOADF(vf, kf, ef, tile)                                              \
  {                                                                          \
    const size_t gb = (size_t)(tile) * 8192;                                 \
    _Pragma("unroll") for (int i = 0; i < 4; ++i) vf[i] =                    \
        *(const half8*)(vtb + gb + i * 1024);                                \
    _Pragma("unroll") for (int j = 0; j < 2; ++j) kf[j] =                    \
        *(const half8*)(ktb + gb + j * 1024);                                \
    _Pragma("unroll") for (int q = 0; q < 4; ++q) ef[q] =                    \
        *(const half8*)(Eb + (size_t)q * SL + (tile) * 32);                  \
  }

#define MFMA32(vf, kf, ef)                                                   \
  {                                                                          \
    __builtin_amdgcn_s_setprio(1);                                           \
    _Pragma("unroll") for (int q = 0; q < 4; ++q) {                          \
      const half8 uk0 = ef[q] * kf[0];                                       \
      const half8 uk1 = ef[q] * kf[1];                                       \
      DOT8(ekr[q][0], ef[q], kf[0])                                          \
      DOT8(ekr[q][1], ef[q], kf[1])                                          \
      _Pragma("unroll") for (int i = 0; i < 4; ++i) {                        \
        acc[q][i][0] = __builtin_amdgcn_mfma_f32_16x16x32_f16(               \
            vf[i], uk0, acc[q][i][0], 0, 0, 0);                              \
        acc[q][i][1] = __builtin_amdgcn_mfma_f32_16x16x32_f16(               \
            vf[i], uk1, acc[q][i][1], 0, 0, 0);                              \
        DOT8(evr[q][i], ef[q], vf[i])                                        \
      }                                                                      \
    }                                                                        \
    __builtin_amdgcn_s_setprio(0);                                           \
  }

  LOADF(vfA, kfA, efA, 0)
  for (int tt = 0; tt < 126; tt += 2) {
    LOADF(vfB, kfB, efB, tt + 1)
    MFMA32(vfA, kfA, efA)
    LOADF(vfA, kfA, efA, tt + 2)
    MFMA32(vfB, kfB, efB)
  }
  LOADF(vfB, kfB, efB, 127)
  MFMA32(vfA, kfA, efA)
  MFMA32(vfB, kfB, efB)
#undef LOADF
#undef MFMA32

  // reduce EV/EK partials across the 4 kc lane-groups (lanes xor 16, 32)
#pragma unroll
  for (int q = 0; q < 4; ++q) {
#pragma unroll
    for (int i = 0; i < 4; ++i) {
      evr[q][i] += __shfl_xor(evr[q][i], 16);
      evr[q][i] += __shfl_xor(evr[q][i], 32);
    }
#pragma unroll
    for (int j = 0; j < 2; ++j) {
      ekr[q][j] += __shfl_xor(ekr[q][j], 16);
      ekr[q][j] += __shfl_xor(ekr[q][j], 32);
    }
  }

  const float scl = 0.08838834764831845f;
  const size_t DS = (size_t)BATCH * NQ;  // denom partial stride
#pragma unroll
  for (int q = 0; q < 4; ++q) {
    const size_t qi = (size_t)b * NQ + q0 + q;
    float den = 0.f;
#pragma unroll
    for (int p = 0; p < 4; ++p) den += denomp[p * DS + qi];
    const float invd = 1.0f / den;
    float* ob = out + qi * DH * DH;
    const int rbase = (l >> 4) * 4;
#pragma unroll
    for (int i = 0; i < 4; ++i) {
      const int row0 = (sA + i) * 16 + rbase;
      float evv[4];
#pragma unroll
      for (int r = 0; r < 4; ++r) evv[r] = __shfl(evr[q][i], rbase + r);
#pragma unroll
      for (int j = 0; j < 2; ++j) {
        const int col = (sB + j) * 16 + (l & 15);
        const float ek = ekr[q][j];
#pragma unroll
        for (int r = 0; r < 4; ++r)
          ob[(size_t)(row0 + r) * DH + col] =
              scl * invd * (acc[q][i][j][r] - invd * evv[r] * ek);
      }
    }
  }
}

extern "C" void kernel_launch(void* const* d_in, const int* in_sizes, int n_in,
                              void* d_out, int out_size, void* d_ws,
                              size_t ws_size, hipStream_t stream) {
  const float* Q = (const float*)d_in[0];
  const float* K = (const float*)d_in[1];
  const float* V = (const float*)d_in[2];
  float* out = (float*)d_out;

  // ws: Vt 16.8MB | Kt 16.8MB | E f16 8.4MB | denomp 16KB
  f16* Vt = (f16*)d_ws;
  f16* Kt = Vt + (size_t)BATCH * DH * SL;
  f16* Ef = Kt + (size_t)BATCH * DH * SL;
  float* denomp = (float*)(Ef + (size_t)BATCH * NQ * SL);

  kprep<<<1024, 256, 0, stream>>>(K, V, Kt, Vt);
  kscore<<<512, 256, 0, stream>>>(Q, Kt, Ef, denomp);
  kjac<<<256, 512, 0, stream>>>(Vt, Kt, Ef, denomp, out);
}

// Round 15
// 176.382 us; speedup vs baseline: 1.3036x; 1.3036x over previous
//
#include <hip/hip_runtime.h>
#include <stdint.h>

typedef _Float16 f16;
typedef _Float16 half4 __attribute__((ext_vector_type(4)));
typedef _Float16 half8 __attribute__((ext_vector_type(8)));
typedef float f32x4 __attribute__((ext_vector_type(4)));

#define BATCH 16
#define NQ 64
#define SL 4096
#define DH 128

// Tiled f16 layout for Kt/Vt, per b (halves):
//   off(d, n) = (n>>5)*4096 + (d>>4)*512 + ((n>>3)&3)*128 + (d&15)*8 + (n&7)
// A fragment read (16x16x32 MFMA) is then a coalesced global read base+l*16.

// ---------------------------------------------------------------------------
// Kernel P: convert f32 [b][n][d] -> f16 tiled [b][(d,n) tiled]
// ---------------------------------------------------------------------------
__global__ __launch_bounds__(256) void kprep(const float* __restrict__ Kg,
                                             const float* __restrict__ Vg,
                                             f16* __restrict__ Kt,
                                             f16* __restrict__ Vt) {
  __shared__ f16 Ld[128][130];
  const int blk = blockIdx.x;
  const int b = blk >> 6;
  const int tensor = (blk >> 5) & 1;
  const int chunk = blk & 31;
  const float* src = tensor ? Vg : Kg;
  f16* dst = tensor ? Vt : Kt;
  const int t = threadIdx.x;
  const int n0 = chunk * 128;
  {
    const int d = t & 127;
    const int nl = t >> 7;  // 0..1
    const float* s = src + ((size_t)b * SL + n0 + nl) * DH + d;
    for (int it = 0; it < 64; ++it)
      Ld[d][nl + it * 2] = (f16)s[(size_t)it * 2 * DH];
  }
  __syncthreads();
  {
    const int r = t & 15;
    const int kc = (t >> 4) & 3;
    const int w = t >> 6;
    char* dstb = (char*)(dst + (size_t)b * DH * SL);
#pragma unroll
    for (int tl = 0; tl < 4; ++tl)
#pragma unroll
      for (int hh = 0; hh < 2; ++hh) {
        const int dhi = w + hh * 4;
        const int d = dhi * 16 + r;
        const int nl = tl * 32 + kc * 8;
        const half8 v = *(const half8*)&Ld[d][nl];
        *(half8*)(dstb + (size_t)(chunk * 4 + tl) * 8192 + dhi * 1024 +
                  kc * 256 + r * 16) = v;
      }
  }
}

// ---------------------------------------------------------------------------
// Kernel S: E[b][q][n] = (f16)exp(scale * Q.K[n]).  Reads tiled Kt.
// Also writes denomp[ns][b][q] = sum_{n in quarter} E  (deterministic).
// ---------------------------------------------------------------------------
__global__ __launch_bounds__(256) void kscore(const float* __restrict__ Q,
                                              const f16* __restrict__ Kt,
                                              f16* __restrict__ E,
                                              float* __restrict__ denomp) {
  const int blk = (blockIdx.x & 7) * 64 + (blockIdx.x >> 3);
  __shared__ float Qs[8][128];
  __shared__ float wsum[4][4];
  const int b = blk >> 5;
  const int qg = (blk >> 2) & 7;
  const int ns = blk & 3;
  const int t = threadIdx.x;
  for (int i = t; i < 8 * 128; i += 256)
    Qs[i >> 7][i & 127] = Q[((size_t)b * NQ + qg * 8 + (i >> 7)) * DH + (i & 127)];
  __syncthreads();
  const int w = t >> 6, l = t & 63;
  const int q0 = (w >> 1) * 4;
  const int nbase = ns * 1024 + (w & 1) * 512 + l * 8;
  const f16* kb = Kt + (size_t)b * DH * SL + (size_t)(nbase >> 5) * 4096 +
                  (size_t)((nbase >> 3) & 3) * 128;
  float acc[4][8] = {};
  for (int d = 0; d < DH; ++d) {
    const half8 kv = *(const half8*)(kb + (d >> 4) * 512 + (d & 15) * 8);
    float kf[8];
#pragma unroll
    for (int j = 0; j < 8; ++j) kf[j] = (float)kv[j];
#pragma unroll
    for (int qi = 0; qi < 4; ++qi) {
      const float qv = Qs[q0 + qi][d];
#pragma unroll
      for (int j = 0; j < 8; ++j) acc[qi][j] += qv * kf[j];
    }
  }
  const float scl = 0.08838834764831845f;  // 1/sqrt(128)
#pragma unroll
  for (int qi = 0; qi < 4; ++qi) {
    half8 ev;
    float ds = 0.f;
#pragma unroll
    for (int j = 0; j < 8; ++j) {
      ev[j] = (f16)__expf(acc[qi][j] * scl);
      ds += (float)ev[j];
    }
    *(half8*)&E[((size_t)b * NQ + qg * 8 + q0 + qi) * SL + nbase] = ev;
    for (int off = 1; off < 64; off <<= 1) ds += __shfl_xor(ds, off);
    if (l == 0) wsum[w][qi] = ds;
  }
  __syncthreads();
  if (t < 8) {
    const int hw = (t >> 2) * 2;
    denomp[(size_t)ns * BATCH * NQ + (size_t)b * NQ + qg * 8 + t] =
        wsum[hw][t & 3] + wsum[hw + 1][t & 3];
  }
}

// ---------------------------------------------------------------------------
// Kernel EVK: EVp[nq][b][q][v] = sum_{n in quarter} E*V (and EK) via MFMA.
// (denominator moved to kscore.)
// ---------------------------------------------------------------------------
__global__ __launch_bounds__(256) void kev(const f16* __restrict__ Vt,
                                           const f16* __restrict__ Kt,
                                           const f16* __restrict__ E,
                                           float* __restrict__ EVp,
                                           float* __restrict__ EKp) {
  __shared__ __align__(16) f16 Es[32][40];
  const int blk = (blockIdx.x & 7) * 32 + (blockIdx.x >> 3);  // XCD swizzle
  const int b = blk >> 4;
  const int tensor = (blk >> 3) & 1;
  const int nq = (blk >> 1) & 3;    // n-quarter (1024 n)
  const int qh = blk & 1;           // q-half (32 q)
  const char* src = (const char*)((tensor ? Kt : Vt) + (size_t)b * DH * SL);
  float* dst = (tensor ? EKp : EVp) +
               ((size_t)nq * BATCH * NQ + (size_t)b * NQ + qh * 32) * DH;
  const f16* Eb = E + ((size_t)b * NQ + qh * 32) * SL + nq * 1024;
  const int t = threadIdx.x, w = t >> 6, l = t & 63;
  const int eq = t >> 3;            // staging: q row 0..31
  const int en = (t & 7) * 4;       // staging: 4 n per thread

  f32x4 acc[2][2] = {};             // [sv2][qsub]

  for (int chunk = 0; chunk < 32; ++chunk) {
    *(half4*)&Es[eq][en] = *(const half4*)(Eb + (size_t)eq * SL + chunk * 32 + en);
    __syncthreads();
    const int n0 = nq * 1024 + chunk * 32;
    const size_t gb = (size_t)(n0 >> 5) * 8192 + l * 16;
    const half8 a0 = *(const half8*)(src + gb + w * 1024);
    const half8 a1 = *(const half8*)(src + gb + (w + 4) * 1024);
    half8 b0, b1;
#pragma unroll
    for (int j = 0; j < 8; ++j) {
      b0[j] = Es[l & 15][(l >> 4) * 8 + j];
      b1[j] = Es[16 + (l & 15)][(l >> 4) * 8 + j];
    }
    acc[0][0] = __builtin_amdgcn_mfma_f32_16x16x32_f16(a0, b0, acc[0][0], 0, 0, 0);
    acc[0][1] = __builtin_amdgcn_mfma_f32_16x16x32_f16(a0, b1, acc[0][1], 0, 0, 0);
    acc[1][0] = __builtin_amdgcn_mfma_f32_16x16x32_f16(a1, b0, acc[1][0], 0, 0, 0);
    acc[1][1] = __builtin_amdgcn_mfma_f32_16x16x32_f16(a1, b1, acc[1][1], 0, 0, 0);
    __syncthreads();
  }

#pragma unroll
  for (int sv2 = 0; sv2 < 2; ++sv2)
#pragma unroll
    for (int qsub = 0; qsub < 2; ++qsub) {
      const int q = qsub * 16 + (l & 15);
      const int row = (w + sv2 * 4) * 16 + (l >> 4) * 4;
      *(f32x4*)&dst[(size_t)q * DH + row] = acc[sv2][qsub];
    }
}

// ---------------------------------------------------------------------------
// Kernel G: per (b, 4 q):  T[v][k] = sum_n V[n,v] * (E_n*K[n,k])  via MFMA.
// R12 shape (512 thr / 8 waves / 1 block per CU, wave 64x32 x 4q), but the
// block's E working set (4 rows = 32KB) is staged into LDS ONCE in the
// prologue; per-tile ef is a broadcast ds_read_b128 (no VMEM, no conflicts).
// Hot-loop VMEM = only the 6 V/K fragment loads.  NO barriers in loop;
// ping-pong distance 1; setprio.  Zero extra registers vs R12.
// ---------------------------------------------------------------------------
__global__ __launch_bounds__(512, 2) void kjac(
    const f16* __restrict__ Vt, const f16* __restrict__ Kt,
    const f16* __restrict__ E, const float* __restrict__ EV,
    const float* __restrict__ EK, const float* __restrict__ denomp,
    float* __restrict__ out) {
  __shared__ __align__(16) f16 El[4][4096];  // 32KB: E rows q0..q0+3
  const int blk = (blockIdx.x & 7) * 32 + (blockIdx.x >> 3);  // XCD swizzle
  const int b = blk >> 4;
  const int q0 = (blk & 15) * 4;
  const int t = threadIdx.x, w = t >> 6, l = t & 63;
  const int sA = (w >> 2) * 4;  // A row-subtile base (row half: 64 rows)
  const int sB = (w & 3) * 2;   // B col-subtile base (col quarter: 32 cols)
  const char* vtb = (const char*)(Vt + (size_t)b * DH * SL) + sA * 1024 + l * 16;
  const char* ktb = (const char*)(Kt + (size_t)b * DH * SL) + sB * 1024 + l * 16;

  // prologue: stage E rows (coalesced 16B/thread x 4 passes), one barrier
  {
    const f16* Eg = E + ((size_t)b * NQ + q0) * SL;
#pragma unroll
    for (int p = 0; p < 4; ++p)
      *(half8*)&El[p][t * 8] = *(const half8*)(Eg + (size_t)p * SL + t * 8);
  }
  __syncthreads();

  f32x4 acc[4][4][2] = {};
  half8 vfA[4], kfA[2], efA[4], vfB[4], kfB[2], efB[4];
  const int eoff = (l >> 4) * 8;

#define LOADF(vf, kf, ef, tile)                                              \
  {                                                                          \
    const size_t gb = (size_t)(tile) * 8192;                                 \
    _Pragma("unroll") for (int i = 0; i < 4; ++i) vf[i] =                    \
        *(const half8*)(vtb + gb + i * 1024);                                \
    _Pragma("unroll") for (int j = 0; j < 2; ++j) kf[j] =                    \
        *(const half8*)(ktb + gb + j * 1024);                                \
    _Pragma("unroll") for (int q = 0; q < 4; ++q) ef[q] =                    \
        *(const half8*)&El[q][(tile) * 32 + eoff];                           \
  }

#define MFMA32(vf, kf, ef)                                                   \
  {                                                                          \
    __builtin_amdgcn_s_setprio(1);                                           \
    _Pragma("unroll") for (int q = 0; q < 4; ++q) {                          \
      const half8 uk0 = ef[q] * kf[0];                                       \
      const half8 uk1 = ef[q] * kf[1];                                       \
      _Pragma("unroll") for (int i = 0; i < 4; ++i) {                        \
        acc[q][i][0] = __builtin_amdgcn_mfma_f32_16x16x32_f16(               \
            vf[i], uk0, acc[q][i][0], 0, 0, 0);                              \
        acc[q][i][1] = __builtin_amdgcn_mfma_f32_16x16x32_f16(               \
            vf[i], uk1, acc[q][i][1], 0, 0, 0);                              \
      }                                                                      \
    }                                                                        \
    __builtin_amdgcn_s_setprio(0);                                           \
  }

  LOADF(vfA, kfA, efA, 0)
  for (int tt = 0; tt < 126; tt += 2) {
    LOADF(vfB, kfB, efB, tt + 1)
    MFMA32(vfA, kfA, efA)
    LOADF(vfA, kfA, efA, tt + 2)
    MFMA32(vfB, kfB, efB)
  }
  LOADF(vfB, kfB, efB, 127)
  MFMA32(vfA, kfA, efA)
  MFMA32(vfB, kfB, efB)
#undef LOADF
#undef MFMA32

  const float scl = 0.08838834764831845f;
  const size_t PS = (size_t)BATCH * NQ * DH;   // partial stride (EV/EK)
  const size_t DS = (size_t)BATCH * NQ;        // partial stride (denom)
#pragma unroll
  for (int q = 0; q < 4; ++q) {
    const size_t qi = (size_t)b * NQ + q0 + q;
    float den = 0.f;
#pragma unroll
    for (int p = 0; p < 4; ++p) den += denomp[p * DS + qi];
    const float invd = 1.0f / den;
    const float* evq = EV + qi * DH;
    const float* ekq = EK + qi * DH;
    float* ob = out + qi * DH * DH;
#pragma unroll
    for (int i = 0; i < 4; ++i) {
      const int row0 = (sA + i) * 16 + (l >> 4) * 4;
      f32x4 ev4 = *(const f32x4*)&evq[row0];
#pragma unroll
      for (int p = 1; p < 4; ++p) ev4 += *(const f32x4*)&evq[p * PS + row0];
#pragma unroll
      for (int j = 0; j < 2; ++j) {
        const int col = (sB + j) * 16 + (l & 15);
        float ek = ekq[col];
#pragma unroll
        for (int p = 1; p < 4; ++p) ek += ekq[p * PS + col];
#pragma unroll
        for (int r = 0; r < 4; ++r)
          ob[(size_t)(row0 + r) * DH + col] =
              scl * invd * (acc[q][i][j][r] - invd * ev4[r] * ek);
      }
    }
  }
}

extern "C" void kernel_launch(void* const* d_in, const int* in_sizes, int n_in,
                              void* d_out, int out_size, void* d_ws,
                              size_t ws_size, hipStream_t stream) {
  const float* Q = (const float*)d_in[0];
  const float* K = (const float*)d_in[1];
  const float* V = (const float*)d_in[2];
  float* out = (float*)d_out;

  // ws: Vt 16.8MB | Kt 16.8MB | E f16 8.4MB | EVp 2MB | EKp 2MB | denomp 16KB
  f16* Vt = (f16*)d_ws;
  f16* Kt = Vt + (size_t)BATCH * DH * SL;
  f16* Ef = Kt + (size_t)BATCH * DH * SL;
  float* EVp = (float*)(Ef + (size_t)BATCH * NQ * SL);
  float* EKp = EVp + 4 * (size_t)BATCH * NQ * DH;
  float* denomp = EKp + 4 * (size_t)BATCH * NQ * DH;

  kprep<<<1024, 256, 0, stream>>>(K, V, Kt, Vt);
  kscore<<<512, 256, 0, stream>>>(Q, Kt, Ef, denomp);
  kev<<<256, 256, 0, stream>>>(Vt, Kt, Ef, EVp, EKp);
  kjac<<<256, 512, 0, stream>>>(Vt, Kt, Ef, EVp, EKp, denomp, out);
}